// Round 11
// baseline (1140.300 us; speedup 1.0000x reference)
//
#include <hip/hip_runtime.h>
#include <hip/hip_bf16.h>

#define EMB 384
#define NPOS 8193   // 2L+1 state positions
#define LAYERS 12
#define BATCH 4
#define PT 32       // positions per workgroup

typedef __attribute__((ext_vector_type(8))) short bf16x8;
typedef __attribute__((ext_vector_type(4))) float f32x4;
typedef __attribute__((ext_vector_type(16))) float f32x16;
typedef __attribute__((ext_vector_type(4))) unsigned short u16x4;

__device__ __forceinline__ float b2f(unsigned short u) {
    union { unsigned int i; float f; } v; v.i = ((unsigned int)u) << 16; return v.f;
}
__device__ __forceinline__ unsigned short f2b(float f) {
    union { float f; unsigned int i; } v; v.f = f;
    unsigned int x = v.i;
    return (unsigned short)((x + 0x7FFFu + ((x >> 16) & 1u)) >> 16);
}

// LDS tile: 768B rows, XOR swizzle on 16B blocks keyed by row&15.
// rows 0..33 = plane0 pos j0..j0+33 (clamped); rows 34..65 = plane1 pos j0+1..j0+32
#define SW(row, inner) ((row) * 768 + ((inner) ^ (((row) & 15) << 4)))

// ---- weight pre-swizzle for 32x32x16 A-fragments:
// W32[layer][chunk(72)][ct(12)][lane(64)][8 bf16]
// chunk 0..23 = center k 0..383, 24..47 = right, 48..71 = left (16 k per chunk)
// lane holds out-channel ch = ct*32 + (lane&31), k = chunk*16 + (lane>>5)*8 + e
__global__ void w_prep(const float* __restrict__ wl, const float* __restrict__ wc,
                       const float* __restrict__ wr, unsigned short* __restrict__ wswz) {
    int idx = blockIdx.x * blockDim.x + threadIdx.x;
    const int total = LAYERS * 72 * 12 * 64;
    if (idx >= total) return;
    int lane = idx & 63;
    int t = idx >> 6;
    int ct = t % 12; t /= 12;
    int chunk = t % 72; t /= 72;
    int layer = t;
    int seg = chunk / 24;
    const float* src = (seg == 0 ? wc : (seg == 1 ? wr : wl)) + (size_t)layer * EMB * EMB;
    int kloc = (chunk % 24) * 16 + ((lane >> 5) << 3);
    int ch = ct * 32 + (lane & 31);
    unsigned short o[8];
#pragma unroll
    for (int e = 0; e < 8; ++e) o[e] = f2b(src[(size_t)ch * EMB + kloc + e]);
    *reinterpret_cast<uint4*>(wswz + (size_t)idx * 8) = *reinterpret_cast<uint4*>(o);
}

// ---- initial state X[b][pos][plane][384] bf16 (interleaved, R4 layout)
__global__ void x_init(const float* __restrict__ embs, const float* __restrict__ mask,
                       unsigned short* __restrict__ X) {
    int idx = blockIdx.x * blockDim.x + threadIdx.x;
    const int total = BATCH * NPOS * 48;
    if (idx >= total) return;
    int dg = idx % 48;
    int t = idx / 48;
    int pos = t % NPOS;
    int b = t / NPOS;
    int d0 = dg * 8;
    const float* m = mask + (size_t)b * EMB + d0;
    const float* p0src;
    if (pos >= 1 && pos <= 4096) p0src = embs + ((size_t)b * 4096 + (pos - 1)) * EMB + d0;
    else if (pos == 8192)        p0src = embs + (size_t)b * 4096 * EMB + d0;
    else                         p0src = m;
    unsigned short o0[8], o1[8];
#pragma unroll
    for (int e = 0; e < 8; ++e) { o0[e] = f2b(p0src[e]); o1[e] = f2b(m[e]); }
    size_t base = ((size_t)b * NPOS + pos) * 2 * EMB + d0;
    *reinterpret_cast<uint4*>(X + base)       = *reinterpret_cast<uint4*>(o0);
    *reinterpret_cast<uint4*>(X + base + EMB) = *reinterpret_cast<uint4*>(o1);
}

#define ZERO16 {0.f,0.f,0.f,0.f,0.f,0.f,0.f,0.f,0.f,0.f,0.f,0.f,0.f,0.f,0.f,0.f}

// ---- one layer (R4 tile, 32x32x16 MFMA): 4 waves x 96 out-channels x 32 pos x 2 planes.
// mfma(W=A, X=B): D col = lane&31 = position, D row = (reg&3)+8*(reg>>2)+4*(lane>>5) = ch%32.
// Neighbor term (plane-independent) computed once into acc0, copied to acc1.
__global__ __launch_bounds__(256, 3) void layer_k(
    const unsigned short* __restrict__ Xin, unsigned short* __restrict__ Xout,
    const unsigned short* __restrict__ W, const float* __restrict__ bias) {
    __shared__ char smem[66 * 768];
    const int tid = threadIdx.x;
    const int b = blockIdx.y;
    const int j0 = blockIdx.x * PT;
    const size_t xbase = (size_t)b * NPOS * 2 * EMB;

    // stage both planes (R4 pattern)
    for (int idx = tid; idx < 66 * 48; idx += 256) {
        int row = idx / 48, cg = idx % 48;
        int pos, plane;
        if (row < 34) { pos = j0 + row; if (pos > 8192) pos = 8192; plane = 0; }
        else          { pos = j0 + 1 + (row - 34); plane = 1; }
        uint4 v = *reinterpret_cast<const uint4*>(Xin + xbase + ((size_t)pos * 2 + plane) * EMB + cg * 8);
        *reinterpret_cast<uint4*>(smem + SW(row, cg * 16)) = v;
    }
    __syncthreads();

    const int lane = tid & 63;
    const int wv = tid >> 6;        // 0..3: ch-tiles wv*3 .. wv*3+2
    const int prow = lane & 31;     // position within tile
    const int kh = lane >> 5;       // k-half

    const bf16x8* Wv = reinterpret_cast<const bf16x8*>(W);

    f32x16 acc0[3] = { ZERO16, ZERO16, ZERO16 };
    f32x16 acc1[3];

    bf16x8 wbufA[6], wbufB[6];
#pragma unroll
    for (int n = 0; n < 3; ++n) {
        wbufA[n]     = Wv[(24 * 12 + wv * 3 + n) * 64 + lane];
        wbufA[3 + n] = Wv[(25 * 12 + wv * 3 + n) * 64 + lane];
    }

    // ---- neighbor phase: chunks 24..47 right (x0[p+2]), 48..71 left (x0[p])
#pragma unroll
    for (int t = 0; t < 24; ++t) {
        bf16x8* cur = (t & 1) ? wbufB : wbufA;
        bf16x8* nxt = (t & 1) ? wbufA : wbufB;
        const int nk0 = (t < 23) ? (26 + 2 * t) : 0;   // chain into center chunks 0,1
#pragma unroll
        for (int n = 0; n < 3; ++n) {
            nxt[n]     = Wv[(nk0 * 12 + wv * 3 + n) * 64 + lane];
            nxt[3 + n] = Wv[((nk0 + 1) * 12 + wv * 3 + n) * 64 + lane];
        }
#pragma unroll
        for (int h = 0; h < 2; ++h) {
            const int chunk = 24 + 2 * t + h;
            const int d = (chunk < 48) ? 2 : 0;
            const int inner = (chunk % 24) * 32 + kh * 16;
            bf16x8 xf = *reinterpret_cast<const bf16x8*>(smem + SW(prow + d, inner));
#pragma unroll
            for (int n = 0; n < 3; ++n)
                acc0[n] = __builtin_amdgcn_mfma_f32_32x32x16_bf16(cur[h * 3 + n], xf, acc0[n], 0, 0, 0);
        }
    }
    // copy plane-independent neighbor result to plane1 accumulators
#pragma unroll
    for (int n = 0; n < 3; ++n) acc1[n] = acc0[n];

    // ---- center phase: chunks 0..23, both planes (shared W fragments)
#pragma unroll
    for (int t = 0; t < 12; ++t) {
        bf16x8* cur = (t & 1) ? wbufB : wbufA;
        bf16x8* nxt = (t & 1) ? wbufA : wbufB;
        if (t < 11) {
            const int nk0 = 2 * t + 2;
#pragma unroll
            for (int n = 0; n < 3; ++n) {
                nxt[n]     = Wv[(nk0 * 12 + wv * 3 + n) * 64 + lane];
                nxt[3 + n] = Wv[((nk0 + 1) * 12 + wv * 3 + n) * 64 + lane];
            }
        }
#pragma unroll
        for (int h = 0; h < 2; ++h) {
            const int inner = (2 * t + h) * 32 + kh * 16;
            bf16x8 x0 = *reinterpret_cast<const bf16x8*>(smem + SW(prow + 1, inner));
            bf16x8 x1 = *reinterpret_cast<const bf16x8*>(smem + SW(34 + prow, inner));
#pragma unroll
            for (int n = 0; n < 3; ++n) {
                acc0[n] = __builtin_amdgcn_mfma_f32_32x32x16_bf16(cur[h * 3 + n], x0, acc0[n], 0, 0, 0);
                acc1[n] = __builtin_amdgcn_mfma_f32_32x32x16_bf16(cur[h * 3 + n], x1, acc1[n], 0, 0, 0);
            }
        }
    }

    // ---- epilogue: bias + relu + residual. Lane holds 16 ch x 1 pos per tile/plane:
    // ch = c*32 + grp*8 + kh*4 + ri  (reg = grp*4 + ri)
#pragma unroll
    for (int n = 0; n < 3; ++n) {
        const int c = wv * 3 + n;
#pragma unroll
        for (int pl = 0; pl < 2; ++pl) {
            const int rrow = pl ? (34 + prow) : (prow + 1);
#pragma unroll
            for (int grp = 0; grp < 4; ++grp) {
                const int chb = c * 32 + grp * 8 + kh * 4;
                f32x4 bv = *reinterpret_cast<const f32x4*>(&bias[chb]);
                u16x4 res = *reinterpret_cast<const u16x4*>(smem + SW(rrow, chb * 2));
#pragma unroll
                for (int ri = 0; ri < 4; ++ri) {
                    float v = (pl ? acc1[n][grp * 4 + ri] : acc0[n][grp * 4 + ri]) + bv[ri];
                    v = fmaxf(v, 0.f) + b2f(res[ri]);
                    if (pl) acc1[n][grp * 4 + ri] = v; else acc0[n][grp * 4 + ri] = v;
                }
            }
        }
    }
    __syncthreads();
    // out-tile rows 0..63: plane0 pos p -> row p, plane1 pos p -> row 32+p
#pragma unroll
    for (int n = 0; n < 3; ++n) {
        const int c = wv * 3 + n;
#pragma unroll
        for (int pl = 0; pl < 2; ++pl) {
            const int orow = pl * 32 + prow;
#pragma unroll
            for (int grp = 0; grp < 4; ++grp) {
                const int chb = c * 32 + grp * 8 + kh * 4;
                u16x4 o;
#pragma unroll
                for (int ri = 0; ri < 4; ++ri)
                    o[ri] = f2b(pl ? acc1[n][grp * 4 + ri] : acc0[n][grp * 4 + ri]);
                *reinterpret_cast<u16x4*>(smem + SW(orow, chb * 2)) = o;
            }
        }
    }
    __syncthreads();
    // coalesced scatter with scramble permutation (+ dups at pt 8192 / 0)
    for (int idx = tid; idx < 64 * 48; idx += 256) {
        int r = idx / 48, cg = idx % 48;
        int plane = r >> 5, p = r & 31;
        int j = j0 + p;
        if (j > 8190) continue;
        int pt = (j & 1) ? ((j + NPOS) >> 1) : ((j >> 1) + 1);
        uint4 val = *reinterpret_cast<uint4*>(smem + SW(r, cg * 16));
        *reinterpret_cast<uint4*>(Xout + xbase + ((size_t)pt * 2 + plane) * EMB + cg * 8) = val;
        if (j == 0)
            *reinterpret_cast<uint4*>(Xout + xbase + ((size_t)8192 * 2 + plane) * EMB + cg * 8) = val;
        if (j == 8189)
            *reinterpret_cast<uint4*>(Xout + xbase + ((size_t)plane) * EMB + cg * 8) = val;
    }
}

// ---- finalize: 13th scramble composed with slice -> out[j] = scan-buffer position (2j+1)
__global__ void finalize(const unsigned short* __restrict__ X, float* __restrict__ out) {
    int idx = blockIdx.x * blockDim.x + threadIdx.x;
    const int total = BATCH * 4096 * 48;
    if (idx >= total) return;
    int dg = idx % 48; int t = idx / 48;
    int j = t % 4096; int b = t / 4096;
    int d0 = dg * 8;
    size_t src0 = ((size_t)b * NPOS + (2 * j + 1)) * 2 * EMB + d0;
    size_t o0 = ((size_t)b * 4096 + j) * EMB + d0;
    size_t o1 = o0 + (size_t)BATCH * 4096 * EMB;
    float v0[8], v1[8];
#pragma unroll
    for (int e = 0; e < 8; ++e) { v0[e] = b2f(X[src0 + e]); v1[e] = b2f(X[src0 + EMB + e]); }
    *reinterpret_cast<float4*>(out + o0)     = *reinterpret_cast<float4*>(&v0[0]);
    *reinterpret_cast<float4*>(out + o0 + 4) = *reinterpret_cast<float4*>(&v0[4]);
    *reinterpret_cast<float4*>(out + o1)     = *reinterpret_cast<float4*>(&v1[0]);
    *reinterpret_cast<float4*>(out + o1 + 4) = *reinterpret_cast<float4*>(&v1[4]);
}

extern "C" void kernel_launch(void* const* d_in, const int* in_sizes, int n_in,
                              void* d_out, int out_size, void* d_ws, size_t ws_size,
                              hipStream_t stream) {
    const float* embs = (const float*)d_in[0];
    const float* mask = (const float*)d_in[1];
    const float* wl   = (const float*)d_in[2];
    const float* wc   = (const float*)d_in[3];
    const float* wr   = (const float*)d_in[4];
    const float* bias = (const float*)d_in[5];

    const size_t XELEMS = (size_t)BATCH * NPOS * 2 * EMB;    // 25,168,896
    unsigned short* X0 = (unsigned short*)d_ws;
    unsigned short* X1 = X0 + XELEMS;
    unsigned short* W  = X1 + XELEMS;                         // 12*72*12*64*8 = 5,308,416 elems

    {
        int total = LAYERS * 72 * 12 * 64;
        w_prep<<<(total + 255) / 256, 256, 0, stream>>>(wl, wc, wr, W);
    }
    {
        int total = BATCH * NPOS * 48;
        x_init<<<(total + 255) / 256, 256, 0, stream>>>(embs, mask, X0);
    }
    unsigned short* bufs[2] = { X0, X1 };
    for (int l = 0; l < LAYERS; ++l) {
        layer_k<<<dim3(256, BATCH), 256, 0, stream>>>(
            bufs[l & 1], bufs[(l + 1) & 1],
            W + (size_t)l * 72 * 12 * 64 * 8, bias + (size_t)l * EMB);
    }
    {
        int total = BATCH * 4096 * 48;
        finalize<<<(total + 255) / 256, 256, 0, stream>>>(bufs[0], (float*)d_out);
    }
}